// Round 10
// baseline (725.257 us; speedup 1.0000x reference)
//
#include <hip/hip_runtime.h>
#include <hip/hip_bf16.h>

#define EPS 1e-8f

constexpr int B_   = 8192;
constexpr int IN_  = 2048;
constexpr int OUT_ = 2048;
constexpr int KA_  = IN_ * 6;   // augmented K: [x, basis0..4] per input feature
constexpr int NT_  = KA_ / 64;  // 192 K-tiles of BK=64

typedef __bf16 bf16x8 __attribute__((ext_vector_type(8)));
typedef float  f32x4  __attribute__((ext_vector_type(4)));

__device__ __forceinline__ ushort f2bf(float f) {
    union { float f; uint u; } v; v.f = f;
    uint u = v.u;
    uint r = u + 0x7fffu + ((u >> 16) & 1u);   // RNE
    return (ushort)(r >> 16);
}

__device__ __forceinline__ void gload16(const void* g, void* l) {
    __builtin_amdgcn_global_load_lds(
        (const __attribute__((address_space(1))) void*)g,
        (__attribute__((address_space(3))) void*)l,
        16, 0, 0);
}

// ---------------------------------------------------------------------------
// Stage A: A_aug[b, i*6+c] bf16.  (unchanged, passed R2-R9)
// ---------------------------------------------------------------------------
__global__ __launch_bounds__(256) void stage_a(const float* __restrict__ x,
                                               const float* __restrict__ grid,
                                               ushort* __restrict__ A) {
    __shared__ __attribute__((aligned(16))) ushort pack[1536];
    const int tid = threadIdx.x;
    const int b0  = blockIdx.x * 16;
    const int i0  = blockIdx.y * 256;
    const int i   = i0 + tid;

    float g[5];
#pragma unroll
    for (int j = 0; j < 5; ++j) g[j] = grid[i * 5 + j];

    float r1[9], r2[9];
    {
        int t = 0;
#pragma unroll
        for (int o = 1; o <= 3; ++o) {
#pragma unroll
            for (int j = 0; j < 5 - o; ++j) {
                int i2 = min(j + o, 4);
                int i3 = min(j + o + 1, 4);
                r1[t] = 1.0f / (g[i2] - g[j] + EPS);
                r2[t] = 1.0f / (g[i3] - g[j + 1] + EPS);
                ++t;
            }
        }
    }

    for (int r = 0; r < 16; ++r) {
        const int b = b0 + r;
        float xv = x[(size_t)b * IN_ + i];
        float diff[5], bas[5];
#pragma unroll
        for (int j = 0; j < 5; ++j) {
            diff[j] = xv - g[j];
            bas[j]  = (diff[j] >= 0.0f && diff[j] < 1.0f) ? 1.0f : 0.0f;
        }
        int t = 0;
#pragma unroll
        for (int o = 1; o <= 3; ++o) {
            float nb[4];
#pragma unroll
            for (int j = 0; j < 5 - o; ++j) {
                int i3 = min(j + o + 1, 4);
                float t1 = (diff[j] - g[j]) * r1[t] * bas[j];
                float t2 = (g[i3] - diff[j]) * r2[t] * bas[j + 1];
                nb[j] = t1 + t2;
                ++t;
            }
#pragma unroll
            for (int j = 0; j < 5 - o; ++j) bas[j] = nb[j];
        }

        pack[tid * 6 + 0] = f2bf(xv);
#pragma unroll
        for (int j = 0; j < 5; ++j) pack[tid * 6 + 1 + j] = f2bf(bas[j]);
        __syncthreads();
        {
            const uint* ps = (const uint*)pack;
            uint* pd = (uint*)(A + (size_t)b * KA_ + (size_t)i0 * 6);
#pragma unroll
            for (int j = 0; j < 3; ++j) pd[tid + j * 256] = ps[tid + j * 256];
        }
        __syncthreads();
    }
}

// ---------------------------------------------------------------------------
// Stage W: W_aug[o, i*6+c] bf16.  (unchanged, passed R2-R9)
// ---------------------------------------------------------------------------
__global__ __launch_bounds__(256) void stage_w(const float* __restrict__ bw,
                                               const float* __restrict__ sw,
                                               ushort* __restrict__ W) {
    __shared__ __attribute__((aligned(16))) float  ssh[1280];
    __shared__ __attribute__((aligned(16))) ushort wsh[1536];
    const int tid = threadIdx.x;
    const int o   = blockIdx.x;
    const int i0  = blockIdx.y * 256;

    const float* sp = sw + ((size_t)o * IN_ + i0) * 5;
    for (int j = tid; j < 1280; j += 256) ssh[j] = sp[j];
    float bwv = bw[(size_t)o * IN_ + i0 + tid];
    __syncthreads();

    wsh[tid * 6] = f2bf(bwv);
#pragma unroll
    for (int j = 0; j < 5; ++j) wsh[tid * 6 + 1 + j] = f2bf(ssh[tid * 5 + j]);
    __syncthreads();

    const uint* ps = (const uint*)wsh;
    uint* pd = (uint*)(W + (size_t)o * KA_ + (size_t)i0 * 6);
#pragma unroll
    for (int j = 0; j < 3; ++j) pd[tid + j * 256] = ps[tid + j * 256];
}

// ---------------------------------------------------------------------------
// GEMM, 256x256 8-phase, W DIRECT-TO-REGISTER (R10):
//   A stays LDS-staged (R6 path, T2-swizzled, 0-conflict).  W (B-operand)
//   loads straight global->reg, double-buffered one K-tile ahead:
//     P1: load bW1 <- W(t1);  P5: load bW0 <- W(t0+2)
//   Cuts LDS traffic 256->160 KB per K-tile (removes B-frag reads 64KB +
//   W staging writes 32KB) -- the measured ~460cyc/phase overhead is LDS
//   pipe serialization (R6-null + R9-worse falsify read-placement theory).
//   Even 4 ds_reads/phase (single a-buffer, rotated per phase).
//   vmcnt(0) at P4/P8 tails BEFORE ENDBAR: drains 3-phase-old loads
//   (~2.7Kcyc >> HBM) -> no stall; barrier then orders all waves' drains
//   before any cross-wave LDS read (formally race-free).
//   Per-acc MFMA order (kh0 then kh1, tile order) identical to R6 ->
//   bitwise-identical output expected.
// grid: 256 blocks (1/CU), XCD-swizzled (256%8==0 -> bijective)
// ---------------------------------------------------------------------------
__global__ __launch_bounds__(512, 2) void gemm_kanw(const ushort* __restrict__ A,
                                                    const ushort* __restrict__ W,
                                                    const float* __restrict__ bias,
                                                    float* __restrict__ out) {
    __shared__ __attribute__((aligned(16))) char lds[2][32768];   // As0, As1

    const int tid  = threadIdx.x;
    const int lane = tid & 63;
    const int wave = tid >> 6;
    const int wr   = wave >> 2;   // 0..1
    const int wc   = wave & 3;    // 0..3

    uint bid = blockIdx.x;
    uint swz = (bid & 7u) * 32u + (bid >> 3);   // XCD-contiguous chunks
    const int bm = (int)(swz >> 3);             // 0..31
    const int bn = (int)(swz & 7u);             // 0..7

    const uint lhi16 = ((uint)lane >> 4) * 16u;
    const uint swx   = ((uint)lane & 7u) << 4;  // (row&7)<<4, row&7 == lane&7
    uint aro[8];
#pragma unroll
    for (int m = 0; m < 8; ++m) aro[m] = (uint)(wr * 128 + m * 16 + (lane & 15)) * 128u;

    // A staging: LDS row c*8+(l>>3), phys slot l&7; global source col
    // (l&7)^((l>>3)&7)  [same 128B segment, lane-permuted]
    const uint srow0 = (uint)wave * 8u + ((uint)lane >> 3);
    const uint gcol  = (((uint)lane & 7u) ^ (((uint)lane >> 3) & 7u)) * 8u;
    const ushort* pA0 = A + (size_t)bm * 256 * KA_ + (size_t)srow0 * KA_ + gcol;
    const ushort* pA1 = pA0 + (size_t)64 * KA_;
    const uint c0off = (uint)wave * 1024u;
    const uint c1off = c0off + 8192u;

    // W per-lane row pointers: frag row = wc*64 + n*16 + (lane&15),
    // frag elems k = kh*32 + (lane>>4)*8 (same layout as the LDS b128 path)
    const ushort* pw[4];
#pragma unroll
    for (int n = 0; n < 4; ++n)
        pw[n] = W + (size_t)(bn * 256 + wc * 64 + n * 16 + (lane & 15)) * KA_
                  + ((lane >> 4) * 8);

    f32x4 acc[8][4];
#pragma unroll
    for (int m = 0; m < 8; ++m)
#pragma unroll
        for (int n = 0; n < 4; ++n)
            acc[m][n] = (f32x4){0.f, 0.f, 0.f, 0.f};

#define DSR(base, ro, kh) (*(const bf16x8*)((base) + (ro) + (((kh) * 64u + lhi16) ^ swx)))

#define STAGE(s, h, kk) do {                                                  \
        uint kc_ = (uint)((kk) < NT_ ? (kk) : 0);                             \
        size_t go_ = (size_t)(h) * 128 * KA_ + (size_t)kc_ * 64;              \
        gload16(pA0 + go_, &lds[s][(h) * 16384 + c0off]);                     \
        gload16(pA1 + go_, &lds[s][(h) * 16384 + c1off]);                     \
    } while (0)

// 8 global B-frag loads (elements offset OFF + kh*32 from pw[n])
#define WL(dst, OFF) do {                                                     \
        _Pragma("unroll") for (int n_ = 0; n_ < 4; ++n_)                      \
        _Pragma("unroll") for (int k_ = 0; k_ < 2; ++k_)                      \
            dst[n_][k_] = *(const bf16x8*)(pw[n_] + (OFF) + k_ * 32);         \
    } while (0)

#define RD4(base, MB, KH) do {                                                \
        _Pragma("unroll") for (int m_ = 0; m_ < 4; ++m_)                      \
            a[m_] = DSR(base, aro[(MB) + m_], KH); } while (0)

#define MIDBAR() do { __builtin_amdgcn_s_barrier();                           \
        asm volatile("s_waitcnt lgkmcnt(0)" ::: "memory");                    \
        __builtin_amdgcn_sched_barrier(0); } while (0)

// 16 independent MFMAs (distinct accumulators)
#define MFMA16(MB, BF, KH) do {                                               \
        __builtin_amdgcn_s_setprio(1);                                        \
        _Pragma("unroll") for (int m_ = 0; m_ < 4; ++m_)                      \
        _Pragma("unroll") for (int n_ = 0; n_ < 4; ++n_)                      \
            acc[(MB)+m_][n_] = __builtin_amdgcn_mfma_f32_16x16x32_bf16(       \
                a[m_], BF[n_][KH], acc[(MB)+m_][n_], 0, 0, 0);                \
        __builtin_amdgcn_s_setprio(0); } while (0)

#define VMC0() asm volatile("s_waitcnt vmcnt(0)" ::: "memory")
#define ENDBAR() __builtin_amdgcn_s_barrier()

    const char* As0 = lds[0];
    const char* As1 = lds[1];

    bf16x8 a[4], bW0[4][2], bW1[4][2];

    // prologue: As0 <- A(0); bW0 <- W(0); drain; barrier
    STAGE(0, 0, 0);
    STAGE(0, 1, 0);
    WL(bW0, 0);
    VMC0();
    __builtin_amdgcn_s_barrier();

    for (int it = 0; it < NT_ / 2; ++it) {
        const int t1 = 2 * it + 1;
        // last-iter clamp: t0+2 == NT_ -> load tile 0 instead (never consumed)
        const int off5 = (2 * it + 2 < NT_) ? 128 : 128 - KA_;
        // P1: STAGE As1<-A(t1); load bW1<-W(t1); rd a(m0-3,kh0); MFMA kh0
        STAGE(1, 0, t1);
        STAGE(1, 1, t1);
        WL(bW1, 64);
        RD4(As0, 0, 0); MIDBAR(); MFMA16(0, bW0, 0); ENDBAR();
        // P2
        RD4(As0, 0, 1); MIDBAR(); MFMA16(0, bW0, 1); ENDBAR();
        // P3
        RD4(As0, 4, 0); MIDBAR(); MFMA16(4, bW0, 0); ENDBAR();
        // P4: drain P1's loads before barrier (3 phases old -> no stall)
        RD4(As0, 4, 1); MIDBAR(); MFMA16(4, bW0, 1); VMC0(); ENDBAR();
        // P5: STAGE As0<-A(t0+2); load bW0<-W(t0+2); switch to slot1/bW1
        STAGE(0, 0, t1 + 1);
        STAGE(0, 1, t1 + 1);
        WL(bW0, off5);
        RD4(As1, 0, 0); MIDBAR(); MFMA16(0, bW1, 0); ENDBAR();
        // P6
        RD4(As1, 0, 1); MIDBAR(); MFMA16(0, bW1, 1); ENDBAR();
        // P7
        RD4(As1, 4, 0); MIDBAR(); MFMA16(4, bW1, 0); ENDBAR();
        // P8: drain P5's loads
        RD4(As1, 4, 1); MIDBAR(); MFMA16(4, bW1, 1); VMC0(); ENDBAR();
        pw[0] += 128; pw[1] += 128; pw[2] += 128; pw[3] += 128;
    }

    // epilogue: C/D layout col=lane&15, row=(lane>>4)*4+j
    const int orow0 = bm * 256 + wr * 128;
    const int ocol0 = bn * 256 + wc * 64;
#pragma unroll
    for (int n = 0; n < 4; ++n) {
        int c = ocol0 + n * 16 + (lane & 15);
        float bv = bias[c];
#pragma unroll
        for (int m = 0; m < 8; ++m) {
            int r0 = orow0 + m * 16 + ((lane >> 4) << 2);
#pragma unroll
            for (int j = 0; j < 4; ++j)
                out[(size_t)(r0 + j) * OUT_ + c] = acc[m][n][j] + bv;
        }
    }
#undef DSR
#undef STAGE
#undef WL
#undef RD4
#undef MIDBAR
#undef MFMA16
#undef VMC0
#undef ENDBAR
}

// ---------------------------------------------------------------------------
// Fallback (no workspace): correct f32 path
// ---------------------------------------------------------------------------
__global__ __launch_bounds__(256) void kan_fallback(const float* __restrict__ x,
                                                    const float* __restrict__ bw,
                                                    const float* __restrict__ bb,
                                                    const float* __restrict__ sw,
                                                    const float* __restrict__ grid,
                                                    float* __restrict__ out) {
    __shared__ float ash[16 * 384];
    const int tid = threadIdx.x;
    const int o   = blockIdx.x * 256 + tid;
    const int b0  = blockIdx.y * 16;
    float acc[16];
#pragma unroll
    for (int r = 0; r < 16; ++r) acc[r] = 0.0f;

    for (int ic = 0; ic < IN_; ic += 64) {
        __syncthreads();
        for (int p = tid; p < 1024; p += 256) {
            int r = p >> 6, ii = p & 63;
            int i = ic + ii;
            float xv = x[(size_t)(b0 + r) * IN_ + i];
            float g[5];
#pragma unroll
            for (int j = 0; j < 5; ++j) g[j] = grid[i * 5 + j];
            float diff[5], bas[5];
#pragma unroll
            for (int j = 0; j < 5; ++j) {
                diff[j] = xv - g[j];
                bas[j]  = (diff[j] >= 0.0f && diff[j] < 1.0f) ? 1.0f : 0.0f;
            }
#pragma unroll
            for (int oo = 1; oo <= 3; ++oo) {
                float nb[4];
#pragma unroll
                for (int j = 0; j < 5 - oo; ++j) {
                    int i2 = min(j + oo, 4);
                    int i3 = min(j + oo + 1, 4);
                    nb[j] = (diff[j] - g[j]) / (g[i2] - g[j] + EPS) * bas[j]
                          + (g[i3] - diff[j]) / (g[i3] - g[j + 1] + EPS) * bas[j + 1];
                }
#pragma unroll
                for (int j = 0; j < 5 - oo; ++j) bas[j] = nb[j];
            }
            float* ap = &ash[r * 384 + ii * 6];
            ap[0] = xv;
#pragma unroll
            for (int j = 0; j < 5; ++j) ap[1 + j] = bas[j];
        }
        __syncthreads();
        for (int ii = 0; ii < 64; ++ii) {
            int i = ic + ii;
            float w0 = bw[(size_t)o * IN_ + i];
            const float* swp = sw + ((size_t)o * IN_ + i) * 5;
            float w1 = swp[0], w2 = swp[1], w3 = swp[2], w4 = swp[3], w5 = swp[4];
#pragma unroll
            for (int r = 0; r < 16; ++r) {
                const float* a = &ash[r * 384 + ii * 6];
                acc[r] += a[0] * w0 + a[1] * w1 + a[2] * w2
                        + a[3] * w3 + a[4] * w4 + a[5] * w5;
            }
        }
    }
    float bv = bb[o];
#pragma unroll
    for (int r = 0; r < 16; ++r)
        out[(size_t)(b0 + r) * OUT_ + o] = acc[r] + bv;
}

extern "C" void kernel_launch(void* const* d_in, const int* in_sizes, int n_in,
                              void* d_out, int out_size, void* d_ws, size_t ws_size,
                              hipStream_t stream) {
    (void)in_sizes; (void)n_in; (void)out_size;
    const float* x    = (const float*)d_in[0];
    const float* bw   = (const float*)d_in[1];
    const float* bb   = (const float*)d_in[2];
    const float* sw   = (const float*)d_in[3];
    const float* grid = (const float*)d_in[4];
    float* out = (float*)d_out;

    const size_t needA = (size_t)B_ * KA_ * sizeof(ushort);
    const size_t needW = (size_t)OUT_ * KA_ * sizeof(ushort);

    if (ws_size >= needA + needW) {
        ushort* A = (ushort*)d_ws;
        ushort* W = A + (size_t)B_ * KA_;
        stage_a<<<dim3(B_ / 16, IN_ / 256), 256, 0, stream>>>(x, grid, A);
        stage_w<<<dim3(OUT_, IN_ / 256), 256, 0, stream>>>(bw, sw, W);
        gemm_kanw<<<dim3(256), 512, 0, stream>>>(A, W, bb, out);
    } else {
        kan_fallback<<<dim3(OUT_ / 256, B_ / 16), 256, 0, stream>>>(x, bw, bb, sw, grid, out);
    }
}

// Round 11
// 417.887 us; speedup vs baseline: 1.7355x; 1.7355x over previous
//
#include <hip/hip_runtime.h>
#include <hip/hip_bf16.h>

#define EPS 1e-8f

constexpr int B_   = 8192;
constexpr int IN_  = 2048;
constexpr int OUT_ = 2048;
constexpr int KA_  = IN_ * 6;   // augmented K: [x, basis0..4] per input feature
constexpr int NT_  = KA_ / 64;  // 192 K-tiles of BK=64

typedef __bf16 bf16x8 __attribute__((ext_vector_type(8)));
typedef float  f32x4  __attribute__((ext_vector_type(4)));

__device__ __forceinline__ ushort f2bf(float f) {
    union { float f; uint u; } v; v.f = f;
    uint u = v.u;
    uint r = u + 0x7fffu + ((u >> 16) & 1u);   // RNE
    return (ushort)(r >> 16);
}

__device__ __forceinline__ void gload16(const void* g, void* l) {
    __builtin_amdgcn_global_load_lds(
        (const __attribute__((address_space(1))) void*)g,
        (__attribute__((address_space(3))) void*)l,
        16, 0, 0);
}

// ---------------------------------------------------------------------------
// Stage A: A_aug[b, i*6+c] bf16.  (unchanged, passed R2-R10)
// ---------------------------------------------------------------------------
__global__ __launch_bounds__(256) void stage_a(const float* __restrict__ x,
                                               const float* __restrict__ grid,
                                               ushort* __restrict__ A) {
    __shared__ __attribute__((aligned(16))) ushort pack[1536];
    const int tid = threadIdx.x;
    const int b0  = blockIdx.x * 16;
    const int i0  = blockIdx.y * 256;
    const int i   = i0 + tid;

    float g[5];
#pragma unroll
    for (int j = 0; j < 5; ++j) g[j] = grid[i * 5 + j];

    float r1[9], r2[9];
    {
        int t = 0;
#pragma unroll
        for (int o = 1; o <= 3; ++o) {
#pragma unroll
            for (int j = 0; j < 5 - o; ++j) {
                int i2 = min(j + o, 4);
                int i3 = min(j + o + 1, 4);
                r1[t] = 1.0f / (g[i2] - g[j] + EPS);
                r2[t] = 1.0f / (g[i3] - g[j + 1] + EPS);
                ++t;
            }
        }
    }

    for (int r = 0; r < 16; ++r) {
        const int b = b0 + r;
        float xv = x[(size_t)b * IN_ + i];
        float diff[5], bas[5];
#pragma unroll
        for (int j = 0; j < 5; ++j) {
            diff[j] = xv - g[j];
            bas[j]  = (diff[j] >= 0.0f && diff[j] < 1.0f) ? 1.0f : 0.0f;
        }
        int t = 0;
#pragma unroll
        for (int o = 1; o <= 3; ++o) {
            float nb[4];
#pragma unroll
            for (int j = 0; j < 5 - o; ++j) {
                int i3 = min(j + o + 1, 4);
                float t1 = (diff[j] - g[j]) * r1[t] * bas[j];
                float t2 = (g[i3] - diff[j]) * r2[t] * bas[j + 1];
                nb[j] = t1 + t2;
                ++t;
            }
#pragma unroll
            for (int j = 0; j < 5 - o; ++j) bas[j] = nb[j];
        }

        pack[tid * 6 + 0] = f2bf(xv);
#pragma unroll
        for (int j = 0; j < 5; ++j) pack[tid * 6 + 1 + j] = f2bf(bas[j]);
        __syncthreads();
        {
            const uint* ps = (const uint*)pack;
            uint* pd = (uint*)(A + (size_t)b * KA_ + (size_t)i0 * 6);
#pragma unroll
            for (int j = 0; j < 3; ++j) pd[tid + j * 256] = ps[tid + j * 256];
        }
        __syncthreads();
    }
}

// ---------------------------------------------------------------------------
// Stage W: W_aug[o, i*6+c] bf16.  (unchanged, passed R2-R10)
// ---------------------------------------------------------------------------
__global__ __launch_bounds__(256) void stage_w(const float* __restrict__ bw,
                                               const float* __restrict__ sw,
                                               ushort* __restrict__ W) {
    __shared__ __attribute__((aligned(16))) float  ssh[1280];
    __shared__ __attribute__((aligned(16))) ushort wsh[1536];
    const int tid = threadIdx.x;
    const int o   = blockIdx.x;
    const int i0  = blockIdx.y * 256;

    const float* sp = sw + ((size_t)o * IN_ + i0) * 5;
    for (int j = tid; j < 1280; j += 256) ssh[j] = sp[j];
    float bwv = bw[(size_t)o * IN_ + i0 + tid];
    __syncthreads();

    wsh[tid * 6] = f2bf(bwv);
#pragma unroll
    for (int j = 0; j < 5; ++j) wsh[tid * 6 + 1 + j] = f2bf(ssh[tid * 5 + j]);
    __syncthreads();

    const uint* ps = (const uint*)wsh;
    uint* pd = (uint*)(W + (size_t)o * KA_ + (size_t)i0 * 6);
#pragma unroll
    for (int j = 0; j < 3; ++j) pd[tid + j * 256] = ps[tid + j * 256];
}

// ---------------------------------------------------------------------------
// GEMM, 256x256 8-phase (R6 skeleton) + R11 EVEN READ DISTRIBUTION:
//   Phase = one (m-half, kh): 16 MFMA (4m x 4n, single kh).  Reads per
//   phase: P1/P2/P5/P6 = 8 b128 (4 a + 4 b), P3/P4/P7/P8 = 4 (a only; b
//   regs still live) -- max 8 vs R6's bursty 16.  Same per-iter totals
//   (each fragment read exactly once); drain bursts no longer exceed the
//   MFMA overlap slack (m201 keeps 4-8 reads/phase for this reason).
//   STAGE schedule / vmcnt(4)@P4,P8 ledger / hazard gaps / T2 swizzle /
//   per-acc kh0->kh1 MFMA order: identical to R6 -> bitwise-same output.
// grid: 256 blocks (1/CU), XCD-swizzled (256%8==0 -> bijective)
// ---------------------------------------------------------------------------
__global__ __launch_bounds__(512, 2) void gemm_kan8(const ushort* __restrict__ A,
                                                    const ushort* __restrict__ W,
                                                    const float* __restrict__ bias,
                                                    float* __restrict__ out) {
    __shared__ __attribute__((aligned(16))) char lds[2][2][32768];

    const int tid  = threadIdx.x;
    const int lane = tid & 63;
    const int wave = tid >> 6;
    const int wr   = wave >> 2;   // 0..1
    const int wc   = wave & 3;    // 0..3

    uint bid = blockIdx.x;
    uint swz = (bid & 7u) * 32u + (bid >> 3);   // XCD-contiguous chunks
    const int bm = (int)(swz >> 3);             // 0..31
    const int bn = (int)(swz & 7u);             // 0..7

    const uint lhi16 = ((uint)lane >> 4) * 16u;
    const uint swx   = ((uint)lane & 7u) << 4;  // (row&7)<<4, row&7 == lane&7
    uint aro[8], wro[4];
#pragma unroll
    for (int m = 0; m < 8; ++m) aro[m] = (uint)(wr * 128 + m * 16 + (lane & 15)) * 128u;
#pragma unroll
    for (int n = 0; n < 4; ++n) wro[n] = (uint)(wc * 64 + n * 16 + (lane & 15)) * 128u;

    // staging: LDS row c*8+(l>>3), phys slot l&7; global source col
    // (l&7)^((l>>3)&7)  [same 128B segment, lane-permuted]
    const uint srow0 = (uint)wave * 8u + ((uint)lane >> 3);
    const uint srow1 = srow0 + 64u;
    const uint gcol  = (((uint)lane & 7u) ^ (((uint)lane >> 3) & 7u)) * 8u;
    const ushort* pA0 = A + (size_t)bm * 256 * KA_ + (size_t)srow0 * KA_ + gcol;
    const ushort* pA1 = A + (size_t)bm * 256 * KA_ + (size_t)srow1 * KA_ + gcol;
    const ushort* pW0 = W + (size_t)bn * 256 * KA_ + (size_t)srow0 * KA_ + gcol;
    const ushort* pW1 = W + (size_t)bn * 256 * KA_ + (size_t)srow1 * KA_ + gcol;
    const uint c0off = (uint)wave * 1024u;
    const uint c1off = c0off + 8192u;

    f32x4 acc[8][4];
#pragma unroll
    for (int m = 0; m < 8; ++m)
#pragma unroll
        for (int n = 0; n < 4; ++n)
            acc[m][n] = (f32x4){0.f, 0.f, 0.f, 0.f};

#define DSR(base, ro, kh) (*(const bf16x8*)((base) + (ro) + (((kh) * 64u + lhi16) ^ swx)))

#define STAGE(s, mat, h, kk, PT0, PT1) do {                                   \
        uint kc_ = (uint)((kk) < NT_ ? (kk) : 0);                             \
        size_t go_ = (size_t)(h) * 128 * KA_ + (size_t)kc_ * 64;              \
        gload16(PT0 + go_, &lds[s][mat][(h) * 16384 + c0off]);                \
        gload16(PT1 + go_, &lds[s][mat][(h) * 16384 + c1off]);                \
    } while (0)

// 4 A-frag reads of one kh into a[.][KH]
#define RDAK(base, mb, KH) do {                                               \
        _Pragma("unroll") for (int m_ = 0; m_ < 4; ++m_)                      \
            a[m_][KH] = DSR(base, aro[(mb) + m_], KH); } while (0)

// 4 B-frag reads of one kh into b[.][KH]
#define RDBK(base, KH) do {                                                   \
        _Pragma("unroll") for (int n_ = 0; n_ < 4; ++n_)                      \
            b[n_][KH] = DSR(base, wro[n_], KH); } while (0)

#define MIDBAR() do { __builtin_amdgcn_s_barrier();                           \
        asm volatile("s_waitcnt lgkmcnt(0)" ::: "memory");                    \
        __builtin_amdgcn_sched_barrier(0); } while (0)

// 16 independent MFMAs: acc[MB+m][n] += a[m][KH] * b[n][KH]
#define MFMA16(MB, KH) do {                                                   \
        __builtin_amdgcn_s_setprio(1);                                        \
        _Pragma("unroll") for (int m_ = 0; m_ < 4; ++m_)                      \
        _Pragma("unroll") for (int n_ = 0; n_ < 4; ++n_)                      \
            acc[(MB)+m_][n_] = __builtin_amdgcn_mfma_f32_16x16x32_bf16(       \
                a[m_][KH], b[n_][KH], acc[(MB)+m_][n_], 0, 0, 0);             \
        __builtin_amdgcn_s_setprio(0); } while (0)

#define ENDBAR() __builtin_amdgcn_s_barrier()

    const char* As0 = lds[0][0]; const char* Ws0 = lds[0][1];
    const char* As1 = lds[1][0]; const char* Ws1 = lds[1][1];

    // prologue: slot0 <- tile0 (A+W), slot1.W <- tile1
    STAGE(0, 0, 0, 0, pA0, pA1);
    STAGE(0, 0, 1, 0, pA0, pA1);
    STAGE(0, 1, 0, 0, pW0, pW1);
    STAGE(0, 1, 1, 0, pW0, pW1);
    STAGE(1, 1, 0, 1, pW0, pW1);
    STAGE(1, 1, 1, 1, pW0, pW1);
    asm volatile("s_waitcnt vmcnt(4)" ::: "memory");
    __builtin_amdgcn_s_barrier();

    bf16x8 a[4][2], b[4][2];

    for (int it = 0; it < NT_ / 2; ++it) {
        const int t1 = 2 * it + 1;
        // P1 (t0, m0-3, kh0): 8 reads; STAGE As1.lo(t1)
        RDAK(As0, 0, 0); RDBK(Ws0, 0);
        STAGE(1, 0, 0, t1, pA0, pA1);
        MIDBAR(); MFMA16(0, 0); ENDBAR();
        // P2 (t0, m0-3, kh1): 8 reads; STAGE As1.hi(t1)
        RDAK(As0, 0, 1); RDBK(Ws0, 1);
        STAGE(1, 0, 1, t1, pA0, pA1);
        MIDBAR(); MFMA16(0, 1); ENDBAR();
        // P3 (t0, m4-7, kh0): 4 reads; STAGE Ws0.lo(t0+2)
        RDAK(As0, 4, 0);
        STAGE(0, 1, 0, t1 + 1, pW0, pW1);
        MIDBAR(); MFMA16(4, 0); ENDBAR();
        // P4 (t0, m4-7, kh1): 4 reads; STAGE Ws0.hi(t0+2); vmcnt(4)
        RDAK(As0, 4, 1);
        STAGE(0, 1, 1, t1 + 1, pW0, pW1);
        asm volatile("s_waitcnt vmcnt(4)" ::: "memory");
        MIDBAR(); MFMA16(4, 1); ENDBAR();
        // P5 (t1, m0-3, kh0): 8 reads from slot1; STAGE As0.lo(t0+2)
        RDAK(As1, 0, 0); RDBK(Ws1, 0);
        STAGE(0, 0, 0, t1 + 1, pA0, pA1);
        MIDBAR(); MFMA16(0, 0); ENDBAR();
        // P6 (t1, m0-3, kh1): 8 reads; STAGE As0.hi(t0+2)
        RDAK(As1, 0, 1); RDBK(Ws1, 1);
        STAGE(0, 0, 1, t1 + 1, pA0, pA1);
        MIDBAR(); MFMA16(0, 1); ENDBAR();
        // P7 (t1, m4-7, kh0): 4 reads; STAGE Ws1.lo(t1+2)
        RDAK(As1, 4, 0);
        STAGE(1, 1, 0, t1 + 2, pW0, pW1);
        MIDBAR(); MFMA16(4, 0); ENDBAR();
        // P8 (t1, m4-7, kh1): 4 reads; STAGE Ws1.hi(t1+2); vmcnt(4)
        RDAK(As1, 4, 1);
        STAGE(1, 1, 1, t1 + 2, pW0, pW1);
        asm volatile("s_waitcnt vmcnt(4)" ::: "memory");
        MIDBAR(); MFMA16(4, 1); ENDBAR();
    }

    // epilogue: C/D layout col=lane&15, row=(lane>>4)*4+j
    const int orow0 = bm * 256 + wr * 128;
    const int ocol0 = bn * 256 + wc * 64;
#pragma unroll
    for (int n = 0; n < 4; ++n) {
        int c = ocol0 + n * 16 + (lane & 15);
        float bv = bias[c];
#pragma unroll
        for (int m = 0; m < 8; ++m) {
            int r0 = orow0 + m * 16 + ((lane >> 4) << 2);
#pragma unroll
            for (int j = 0; j < 4; ++j)
                out[(size_t)(r0 + j) * OUT_ + c] = acc[m][n][j] + bv;
        }
    }
#undef DSR
#undef STAGE
#undef RDAK
#undef RDBK
#undef MIDBAR
#undef MFMA16
#undef ENDBAR
}

// ---------------------------------------------------------------------------
// Fallback (no workspace): correct f32 path
// ---------------------------------------------------------------------------
__global__ __launch_bounds__(256) void kan_fallback(const float* __restrict__ x,
                                                    const float* __restrict__ bw,
                                                    const float* __restrict__ bb,
                                                    const float* __restrict__ sw,
                                                    const float* __restrict__ grid,
                                                    float* __restrict__ out) {
    __shared__ float ash[16 * 384];
    const int tid = threadIdx.x;
    const int o   = blockIdx.x * 256 + tid;
    const int b0  = blockIdx.y * 16;
    float acc[16];
#pragma unroll
    for (int r = 0; r < 16; ++r) acc[r] = 0.0f;

    for (int ic = 0; ic < IN_; ic += 64) {
        __syncthreads();
        for (int p = tid; p < 1024; p += 256) {
            int r = p >> 6, ii = p & 63;
            int i = ic + ii;
            float xv = x[(size_t)(b0 + r) * IN_ + i];
            float g[5];
#pragma unroll
            for (int j = 0; j < 5; ++j) g[j] = grid[i * 5 + j];
            float diff[5], bas[5];
#pragma unroll
            for (int j = 0; j < 5; ++j) {
                diff[j] = xv - g[j];
                bas[j]  = (diff[j] >= 0.0f && diff[j] < 1.0f) ? 1.0f : 0.0f;
            }
#pragma unroll
            for (int oo = 1; oo <= 3; ++oo) {
                float nb[4];
#pragma unroll
                for (int j = 0; j < 5 - oo; ++j) {
                    int i2 = min(j + oo, 4);
                    int i3 = min(j + oo + 1, 4);
                    nb[j] = (diff[j] - g[j]) / (g[i2] - g[j] + EPS) * bas[j]
                          + (g[i3] - diff[j]) / (g[i3] - g[j + 1] + EPS) * bas[j + 1];
                }
#pragma unroll
                for (int j = 0; j < 5 - oo; ++j) bas[j] = nb[j];
            }
            float* ap = &ash[r * 384 + ii * 6];
            ap[0] = xv;
#pragma unroll
            for (int j = 0; j < 5; ++j) ap[1 + j] = bas[j];
        }
        __syncthreads();
        for (int ii = 0; ii < 64; ++ii) {
            int i = ic + ii;
            float w0 = bw[(size_t)o * IN_ + i];
            const float* swp = sw + ((size_t)o * IN_ + i) * 5;
            float w1 = swp[0], w2 = swp[1], w3 = swp[2], w4 = swp[3], w5 = swp[4];
#pragma unroll
            for (int r = 0; r < 16; ++r) {
                const float* a = &ash[r * 384 + ii * 6];
                acc[r] += a[0] * w0 + a[1] * w1 + a[2] * w2
                        + a[3] * w3 + a[4] * w4 + a[5] * w5;
            }
        }
    }
    float bv = bb[o];
#pragma unroll
    for (int r = 0; r < 16; ++r)
        out[(size_t)(b0 + r) * OUT_ + o] = acc[r] + bv;
}

extern "C" void kernel_launch(void* const* d_in, const int* in_sizes, int n_in,
                              void* d_out, int out_size, void* d_ws, size_t ws_size,
                              hipStream_t stream) {
    (void)in_sizes; (void)n_in; (void)out_size;
    const float* x    = (const float*)d_in[0];
    const float* bw   = (const float*)d_in[1];
    const float* bb   = (const float*)d_in[2];
    const float* sw   = (const float*)d_in[3];
    const float* grid = (const float*)d_in[4];
    float* out = (float*)d_out;

    const size_t needA = (size_t)B_ * KA_ * sizeof(ushort);
    const size_t needW = (size_t)OUT_ * KA_ * sizeof(ushort);

    if (ws_size >= needA + needW) {
        ushort* A = (ushort*)d_ws;
        ushort* W = A + (size_t)B_ * KA_;
        stage_a<<<dim3(B_ / 16, IN_ / 256), 256, 0, stream>>>(x, grid, A);
        stage_w<<<dim3(OUT_, IN_ / 256), 256, 0, stream>>>(bw, sw, W);
        gemm_kan8<<<dim3(256), 512, 0, stream>>>(A, W, bb, out);
    } else {
        kan_fallback<<<dim3(OUT_ / 256, B_ / 16), 256, 0, stream>>>(x, bw, bb, sw, grid, out);
    }
}